// Round 4
// baseline (124138.708 us; speedup 1.0000x reference)
//
#include <hip/hip_runtime.h>

typedef _Float16 f16;
typedef f16 f16x2 __attribute__((ext_vector_type(2)));
typedef f16 f16x4 __attribute__((ext_vector_type(4)));
typedef f16 f16x8 __attribute__((ext_vector_type(8)));
typedef float f32x4 __attribute__((ext_vector_type(4)));
typedef unsigned int u32;
typedef unsigned long long u64;

#define R 4096
#define IN_DIM 256
#define T_STEPS 4096
#define NBLK 32
#define TPB 1024
#define WPB 16
#define RPW 8                     // rows per wave
#define ROWS_PER_BLK (WPB * RPW)  // 128
#define POLLW (WPB - 1)

// ---- W f32 -> fp16 conversion (re-run every call; deterministic) ----
__global__ void wconv_kernel(const float* __restrict__ W, f16* __restrict__ Wh) {
    size_t i = ((size_t)blockIdx.x * 256 + threadIdx.x) * 4;
    f32x4 v = *(const f32x4*)(W + i);
    f16x4 o = { (f16)v.x, (f16)v.y, (f16)v.z, (f16)v.w };
    *(f16x4*)(Wh + i) = o;
}

// ---- persistent scan: 32 blocks x 16 waves, 8 rows/wave, W from L2 ----
__global__ __launch_bounds__(TPB) void esn_kernel(
    const float* __restrict__ x,      // [T][256]
    const float* __restrict__ Win,    // [R][256]
    const f16*   __restrict__ W,      // [R][R] fp16
    f16* hbuf0, f16* hbuf1,           // [R] fp16 state, double-buffered (zeroed)
    u32* counter,                     // single monotone barrier counter (zeroed)
    const float* __restrict__ Wout,   // [256][R]
    const float* __restrict__ bias,   // [256]
    float* __restrict__ out)          // [256]
{
    __shared__ f16   h_lds[R];        // 8 KB staged h
    __shared__ float x_lds[IN_DIM];

    const int tid  = threadIdx.x;
    const int b    = blockIdx.x;
    const int wave = tid >> 6;
    const int lane = tid & 63;
    const int rowbase = b * ROWS_PER_BLK + wave * RPW;

    // one-time preload: Win fragments (8 x f32x4 = 32 VGPRs, reused 4096x)
    f32x4 winreg[RPW];
#pragma unroll
    for (int r = 0; r < RPW; ++r)
        winreg[r] = *(const f32x4*)(Win + (size_t)(rowbase + r) * IN_DIM + lane * 4);

    const f16* wbase = W + (size_t)rowbase * R;

    for (int t = 0; t < T_STEPS; ++t) {
        // waves 0-3 prefetch x[t] while wave 15 observes the barrier
        if (tid < IN_DIM) x_lds[tid] = x[(size_t)t * IN_DIM + tid];

        // single-line spin, RELAXED loads (sc1 -> L3, no per-poll inv), sleep
        if (t > 0 && wave == POLLW && lane == 0) {
            const u32 tgt = (u32)(NBLK * t);
            while (__hip_atomic_load(counter, __ATOMIC_RELAXED,
                                     __HIP_MEMORY_SCOPE_AGENT) < tgt) {
                __builtin_amdgcn_s_sleep(1);
                asm volatile("" ::: "memory");
            }
        }
        __syncthreads();  // #1: h_t visible (producers drained before adding)

        const f16* h_in  = (t & 1) ? hbuf1 : hbuf0;
        f16*       h_out = (t & 1) ? hbuf0 : hbuf1;

        // stage h_in (8 KB, sc1 loads straight from L3)
        {
            u64 v = __hip_atomic_load((const u64*)h_in + tid, __ATOMIC_RELAXED,
                                      __HIP_MEMORY_SCOPE_AGENT);
            *((u64*)h_lds + tid) = v;
        }
        __syncthreads();  // #2

        // 8-row dot: h chunk read once from LDS, 8 W-row streams from L2
        float acc[RPW];
#pragma unroll
        for (int r = 0; r < RPW; ++r) acc[r] = 0.f;

#pragma unroll
        for (int c = 0; c < 8; ++c) {
            const int off = (c * 64 + lane) * 8;
            const f16x8 hv = *(const f16x8*)(h_lds + off);
            const f16x2 h0 = { hv[0], hv[1] }, h1 = { hv[2], hv[3] };
            const f16x2 h2 = { hv[4], hv[5] }, h3 = { hv[6], hv[7] };
#pragma unroll
            for (int r = 0; r < RPW; ++r) {
                const f16x8 wv = *(const f16x8*)(wbase + (size_t)r * R + off);
                const f16x2 w0 = { wv[0], wv[1] }, w1 = { wv[2], wv[3] };
                const f16x2 w2 = { wv[4], wv[5] }, w3 = { wv[6], wv[7] };
                float a = acc[r];
                a = __builtin_amdgcn_fdot2(w0, h0, a, false);
                a = __builtin_amdgcn_fdot2(w1, h1, a, false);
                a = __builtin_amdgcn_fdot2(w2, h2, a, false);
                a = __builtin_amdgcn_fdot2(w3, h3, a, false);
                acc[r] = a;
            }
        }
        // fused input projection
        {
            const f32x4 xv = *(const f32x4*)(&x_lds[lane * 4]);
#pragma unroll
            for (int r = 0; r < RPW; ++r) {
                acc[r] = fmaf(winreg[r].x, xv.x, acc[r]);
                acc[r] = fmaf(winreg[r].y, xv.y, acc[r]);
                acc[r] = fmaf(winreg[r].z, xv.z, acc[r]);
                acc[r] = fmaf(winreg[r].w, xv.w, acc[r]);
            }
        }
        // butterfly reduce each row (result replicated across lanes)
#pragma unroll
        for (int r = 0; r < RPW; ++r)
#pragma unroll
            for (int off = 32; off > 0; off >>= 1)
                acc[r] += __shfl_xor(acc[r], off, 64);

        // lanes 0,1 publish 4 rows each as one u64 (static acc indexing)
        {
            const bool hi = (lane & 1);
            const float s0 = hi ? acc[4] : acc[0];
            const float s1 = hi ? acc[5] : acc[1];
            const float s2 = hi ? acc[6] : acc[2];
            const float s3 = hi ? acc[7] : acc[3];
            if (lane < 2) {
                f16x4 pv = { (f16)tanhf(s0), (f16)tanhf(s1),
                             (f16)tanhf(s2), (f16)tanhf(s3) };
                u64 bits;
                __builtin_memcpy(&bits, &pv, 8);
                __hip_atomic_store((u64*)(h_out + rowbase) + lane, bits,
                                   __ATOMIC_RELAXED, __HIP_MEMORY_SCOPE_AGENT);
            }
        }
        // drain this wave's sc1 stores to L3, then block-wide order, then add
        asm volatile("s_waitcnt vmcnt(0)" ::: "memory");
        __syncthreads();  // #3
        if (tid == 0)
            __hip_atomic_fetch_add(counter, 1u, __ATOMIC_RELAXED,
                                   __HIP_MEMORY_SCOPE_AGENT);
    }

    // ---- epilogue: wait for final h, out = Wout @ h_T + bias ----
    if (wave == POLLW && lane == 0) {
        const u32 tgt = (u32)NBLK * (u32)T_STEPS;
        while (__hip_atomic_load(counter, __ATOMIC_RELAXED,
                                 __HIP_MEMORY_SCOPE_AGENT) < tgt) {
            __builtin_amdgcn_s_sleep(1);
            asm volatile("" ::: "memory");
        }
    }
    __syncthreads();
    {
        const f16* hf = hbuf0;  // T even -> final state in buffer 0
        u64 v = __hip_atomic_load((const u64*)hf + tid, __ATOMIC_RELAXED,
                                  __HIP_MEMORY_SCOPE_AGENT);
        *((u64*)h_lds + tid) = v;
    }
    __syncthreads();
    if (wave < 8) {  // 8 outputs per block: j = b*8 + wave
        const int j = b * 8 + wave;
        const float* worow = Wout + (size_t)j * R;
        float acc = 0.f;
#pragma unroll
        for (int g = 0; g < 16; ++g) {
            const int idx = g * 256 + lane * 4;
            const f32x4 wv = *(const f32x4*)(worow + idx);
            const f16x4 hv = *(const f16x4*)(h_lds + idx);
            acc = fmaf(wv.x, (float)hv[0], acc);
            acc = fmaf(wv.y, (float)hv[1], acc);
            acc = fmaf(wv.z, (float)hv[2], acc);
            acc = fmaf(wv.w, (float)hv[3], acc);
        }
#pragma unroll
        for (int off = 32; off > 0; off >>= 1)
            acc += __shfl_xor(acc, off, 64);
        if (lane == 0) out[j] = acc + bias[j];
    }
}

extern "C" void kernel_launch(void* const* d_in, const int* in_sizes, int n_in,
                              void* d_out, int out_size, void* d_ws, size_t ws_size,
                              hipStream_t stream) {
    const float* x    = (const float*)d_in[0];
    const float* Win  = (const float*)d_in[1];
    const float* W    = (const float*)d_in[2];
    const float* Wout = (const float*)d_in[3];
    const float* bias = (const float*)d_in[4];
    float* out = (float*)d_out;

    char* ws = (char*)d_ws;
    u32* counter = (u32*)ws;               // own line @ 0
    f16* h0      = (f16*)(ws + 8192);      // 8 KB
    f16* h1      = (f16*)(ws + 16384);     // 8 KB
    f16* Wh      = (f16*)(ws + 65536);     // 32 MB

    // zero counter + h buffers every call (graph-capturable memset node)
    hipMemsetAsync(ws, 0, 32768, stream);

    wconv_kernel<<<(R * (size_t)R) / (256 * 4), 256, 0, stream>>>(W, Wh);
    esn_kernel<<<NBLK, TPB, 0, stream>>>(x, Win, Wh, h0, h1, counter,
                                         Wout, bias, out);
}

// Round 5
// 15963.808 us; speedup vs baseline: 7.7763x; 7.7763x over previous
//
#include <hip/hip_runtime.h>

typedef _Float16 f16;
typedef f16 f16x2 __attribute__((ext_vector_type(2)));
typedef f16 f16x4 __attribute__((ext_vector_type(4)));
typedef f16 f16x8 __attribute__((ext_vector_type(8)));
typedef float f32x4 __attribute__((ext_vector_type(4)));
typedef unsigned int u32;
typedef unsigned long long u64;

#define R 4096
#define IN_DIM 256
#define T_STEPS 4096
#define NBLK 256
#define TPB 1024
#define WPB 16
#define POLLW (WPB - 1)

// ---- W f32 -> fp16 conversion (re-run every call; deterministic) ----
__global__ void wconv_kernel(const float* __restrict__ W, f16* __restrict__ Wh) {
    size_t i = ((size_t)blockIdx.x * 256 + threadIdx.x) * 4;
    f32x4 v = *(const f32x4*)(W + i);
    f16x4 o = { (f16)v.x, (f16)v.y, (f16)v.z, (f16)v.w };
    *(f16x4*)(Wh + i) = o;
}

// ---- persistent scan: 256 blocks x 16 waves, 1 row/wave, W in VGPRs,
// ---- tag-vector barrier: no atomics, relaxed sc1 + vmcnt-drain protocol ----
__global__ __launch_bounds__(TPB) void esn_kernel(
    const float* __restrict__ x,      // [T][256]
    const float* __restrict__ Win,    // [R][256]
    const f16*   __restrict__ W,      // [R][R] fp16
    f16* hb0, f16* hb1,               // [R] fp16 state, double-buffered (zeroed)
    u32* tags0, u32* tags1,           // [NBLK] packed publish tags (zeroed)
    const float* __restrict__ Wout,   // [256][R]
    const float* __restrict__ bias,   // [256]
    float* __restrict__ out)          // [256]
{
    __shared__ f16   h_lds[R];        // 8 KB staged h
    __shared__ float x_lds[IN_DIM];
    __shared__ float red[WPB];

    const int tid  = threadIdx.x;
    const int b    = blockIdx.x;
    const int wave = tid >> 6;
    const int lane = tid & 63;
    const int row  = b * WPB + wave;

    // one-time preload: W row (32 VGPRs) + Win fragment (4 VGPRs)
    f16x8 wreg[8];
    {
        const f16* wrow = W + (size_t)row * R;
#pragma unroll
        for (int c = 0; c < 8; ++c)
            wreg[c] = *(const f16x8*)(wrow + (c * 64 + lane) * 8);
    }
    const f32x4 winreg = *(const f32x4*)(Win + (size_t)row * IN_DIM + lane * 4);

    for (int t = 0; t < T_STEPS; ++t) {
        // waves 0-3 prefetch x[t] while wave 15 polls the tag vector
        if (tid < IN_DIM) x_lds[tid] = x[(size_t)t * IN_DIM + tid];

        const int p = t & 1;
        const f16* h_in   = p ? hb1 : hb0;
        const u32* tg_in  = p ? tags1 : tags0;

        // ---- tag-vector poll: 256 tags in 16 lines, 2 u64 loads per lane ----
        if (wave == POLLW) {
            const u64* tp = (const u64*)tg_in + (size_t)lane * 2;
            const u32 tt = (u32)t;
            for (;;) {
                u64 a = __hip_atomic_load(tp,     __ATOMIC_RELAXED, __HIP_MEMORY_SCOPE_AGENT);
                u64 c = __hip_atomic_load(tp + 1, __ATOMIC_RELAXED, __HIP_MEMORY_SCOPE_AGENT);
                bool ok = ((u32)a >= tt) & ((u32)(a >> 32) >= tt)
                        & ((u32)c >= tt) & ((u32)(c >> 32) >= tt);
                if (__all(ok)) break;
                __builtin_amdgcn_s_sleep(1);
            }
        }
        __syncthreads();  // #1: all tags >= t -> h_t fully visible in L3

        // ---- stage h_t (8 KB, sc1 loads from L3) ----
        {
            u64 v = __hip_atomic_load((const u64*)h_in + tid, __ATOMIC_RELAXED,
                                      __HIP_MEMORY_SCOPE_AGENT);
            *((u64*)h_lds + tid) = v;
        }
        __syncthreads();  // #2

        // ---- dot(W[row,:], h): 8 ds_read_b128 + 32 fdot2, 4 acc chains ----
        float a0 = 0.f, a1 = 0.f, a2 = 0.f, a3 = 0.f;
#pragma unroll
        for (int c = 0; c < 8; ++c) {
            const f16x8 hv = *(const f16x8*)(h_lds + (c * 64 + lane) * 8);
            const f16x2 h0 = { hv[0], hv[1] }, h1 = { hv[2], hv[3] };
            const f16x2 h2 = { hv[4], hv[5] }, h3 = { hv[6], hv[7] };
            const f16x2 w0 = { wreg[c][0], wreg[c][1] }, w1 = { wreg[c][2], wreg[c][3] };
            const f16x2 w2 = { wreg[c][4], wreg[c][5] }, w3 = { wreg[c][6], wreg[c][7] };
            a0 = __builtin_amdgcn_fdot2(w0, h0, a0, false);
            a1 = __builtin_amdgcn_fdot2(w1, h1, a1, false);
            a2 = __builtin_amdgcn_fdot2(w2, h2, a2, false);
            a3 = __builtin_amdgcn_fdot2(w3, h3, a3, false);
        }
        float acc = (a0 + a1) + (a2 + a3);
        {
            const f32x4 xv = *(const f32x4*)(&x_lds[lane * 4]);
            acc = fmaf(winreg.x, xv.x, acc);
            acc = fmaf(winreg.y, xv.y, acc);
            acc = fmaf(winreg.z, xv.z, acc);
            acc = fmaf(winreg.w, xv.w, acc);
        }
#pragma unroll
        for (int off = 32; off > 0; off >>= 1)
            acc += __shfl_xor(acc, off, 64);

        if (lane == 0) red[wave] = tanhf(acc);
        __syncthreads();  // #3: red[] complete

        // ---- publish: 32 B data -> drain to L3 -> tag store (no atomics) ----
        if (wave == POLLW) {
            f16* h_out  = p ? hb0 : hb1;
            u32* tg_out = p ? tags0 : tags1;
            if (lane < 4) {
                f16x4 pv = { (f16)red[lane * 4 + 0], (f16)red[lane * 4 + 1],
                             (f16)red[lane * 4 + 2], (f16)red[lane * 4 + 3] };
                u64 bits;
                __builtin_memcpy(&bits, &pv, 8);
                __hip_atomic_store((u64*)(h_out + b * WPB) + lane, bits,
                                   __ATOMIC_RELAXED, __HIP_MEMORY_SCOPE_AGENT);
            }
            asm volatile("s_waitcnt vmcnt(0)" ::: "memory");  // data at L3
            if (lane == 0)
                __hip_atomic_store(tg_out + b, (u32)(t + 1), __ATOMIC_RELAXED,
                                   __HIP_MEMORY_SCOPE_AGENT);
        }
        // no trailing barrier: other waves wait at #1; POLLW rejoins there
    }

    // ---- epilogue: wait for h_T (parity 0), out = Wout @ h_T + bias ----
    if (wave == POLLW) {
        const u64* tp = (const u64*)tags0 + (size_t)lane * 2;
        const u32 tt = (u32)T_STEPS;
        for (;;) {
            u64 a = __hip_atomic_load(tp,     __ATOMIC_RELAXED, __HIP_MEMORY_SCOPE_AGENT);
            u64 c = __hip_atomic_load(tp + 1, __ATOMIC_RELAXED, __HIP_MEMORY_SCOPE_AGENT);
            bool ok = ((u32)a >= tt) & ((u32)(a >> 32) >= tt)
                    & ((u32)c >= tt) & ((u32)(c >> 32) >= tt);
            if (__all(ok)) break;
            __builtin_amdgcn_s_sleep(1);
        }
    }
    __syncthreads();
    {
        u64 v = __hip_atomic_load((const u64*)hb0 + tid, __ATOMIC_RELAXED,
                                  __HIP_MEMORY_SCOPE_AGENT);
        *((u64*)h_lds + tid) = v;
    }
    __syncthreads();
    {
        const float* worow = Wout + (size_t)b * R;
        const f32x4 wv = *(const f32x4*)(worow + tid * 4);
        float acc = wv.x * (float)h_lds[tid * 4 + 0]
                  + wv.y * (float)h_lds[tid * 4 + 1]
                  + wv.z * (float)h_lds[tid * 4 + 2]
                  + wv.w * (float)h_lds[tid * 4 + 3];
#pragma unroll
        for (int off = 32; off > 0; off >>= 1)
            acc += __shfl_xor(acc, off, 64);
        if (lane == 0) red[wave] = acc;
        __syncthreads();
        if (tid == 0) {
            float s = bias[b];
#pragma unroll
            for (int w = 0; w < WPB; ++w) s += red[w];
            out[b] = s;
        }
    }
}

extern "C" void kernel_launch(void* const* d_in, const int* in_sizes, int n_in,
                              void* d_out, int out_size, void* d_ws, size_t ws_size,
                              hipStream_t stream) {
    const float* x    = (const float*)d_in[0];
    const float* Win  = (const float*)d_in[1];
    const float* W    = (const float*)d_in[2];
    const float* Wout = (const float*)d_in[3];
    const float* bias = (const float*)d_in[4];
    float* out = (float*)d_out;

    char* ws = (char*)d_ws;
    u32* tags0 = (u32*)ws;                 // 1 KB @ 0
    u32* tags1 = (u32*)(ws + 4096);        // 1 KB
    f16* h0    = (f16*)(ws + 16384);       // 8 KB
    f16* h1    = (f16*)(ws + 24576);       // 8 KB
    f16* Wh    = (f16*)(ws + 65536);       // 32 MB

    // zero tags + h buffers every call (graph-capturable memset node)
    hipMemsetAsync(ws, 0, 65536, stream);

    wconv_kernel<<<(R * (size_t)R) / (256 * 4), 256, 0, stream>>>(W, Wh);
    esn_kernel<<<NBLK, TPB, 0, stream>>>(x, Win, Wh, h0, h1, tags0, tags1,
                                         Wout, bias, out);
}